// Round 4
// baseline (889.945 us; speedup 1.0000x reference)
//
#include <hip/hip_runtime.h>
#include <cstdint>
#include <cstddef>

constexpr int DIMS = 128;

typedef __attribute__((ext_vector_type(8))) short bf16x8;
typedef __attribute__((ext_vector_type(8))) unsigned short ushort8v;
typedef __attribute__((ext_vector_type(4))) float f32x4;

__device__ __forceinline__ unsigned short f2b(float f) {
    uint32_t u = __builtin_bit_cast(uint32_t, f);
    uint32_t r = (u + 0x7FFFu + ((u >> 16) & 1u)) >> 16;
    return (unsigned short)r;
}
__device__ __forceinline__ float b2f(unsigned short h) {
    uint32_t u = ((uint32_t)h) << 16;
    return __builtin_bit_cast(float, u);
}

// ---------------- degree ----------------
__global__ void k_count(const int* __restrict__ dst, int* __restrict__ cnt, int E) {
    int e = blockIdx.x * blockDim.x + threadIdx.x;
    if (e < E) atomicAdd(&cnt[dst[e]], 1);
}

__global__ void k_dinv2(const int* __restrict__ cnt, float* __restrict__ dinv, int N) {
    int i = blockIdx.x * blockDim.x + threadIdx.x;
    if (i < N) dinv[i] = rsqrtf((float)(cnt[i] + 1));
}

// bump-allocated CSR row offsets (buckets need not be ordered)
__global__ void k_alloc(const int* __restrict__ cnt, int* __restrict__ row_ptr,
                        int* __restrict__ bump, int N) {
    int i = blockIdx.x * blockDim.x + threadIdx.x;
    int lane = threadIdx.x & 63;
    int v = (i < N) ? cnt[i] : 0;
    int x = v;
#pragma unroll
    for (int d = 1; d < 64; d <<= 1) {
        int y = __shfl_up(x, d);
        if (lane >= d) x += y;
    }
    int total = __shfl(x, 63);
    int base = 0;
    if (lane == 0) base = atomicAdd(bump, total);
    base = __shfl(base, 0);
    if (i < N) row_ptr[i] = base + x - v;
}

__global__ void k_fill(const int* __restrict__ src, const int* __restrict__ dst,
                       const int* __restrict__ row_ptr, int* __restrict__ cursor,
                       const float* __restrict__ dinv,
                       int* __restrict__ col, float* __restrict__ wgt, int E) {
    int e = blockIdx.x * blockDim.x + threadIdx.x;
    if (e >= E) return;
    int s = src[e], d = dst[e];
    int pos = row_ptr[d] + atomicAdd(&cursor[d], 1);
    col[pos] = s;
    wgt[pos] = dinv[s] * dinv[d];
}

// ---------------- f32 -> bf16 row cast (8 elems/thread) ----------------
__global__ void k_cast(const float* __restrict__ X, unsigned short* __restrict__ Y, int n8) {
    int i = blockIdx.x * blockDim.x + threadIdx.x;
    if (i >= n8) return;
    const float4* p = (const float4*)X + (size_t)i * 2;
    float4 a = p[0], b = p[1];
    ushort8v o;
    o[0] = f2b(a.x); o[1] = f2b(a.y); o[2] = f2b(a.z); o[3] = f2b(a.w);
    o[4] = f2b(b.x); o[5] = f2b(b.y); o[6] = f2b(b.z); o[7] = f2b(b.w);
    *(ushort8v*)&Y[(size_t)i * 8] = o;
}

// ---------------- W pack (hi only): f32 [128][128] -> bf16 MFMA B-fragments ----
// frag index t = (kk*8+nt)*64+lane ; element j = W[kk*32+(lane>>4)*8+j][nt*16+(lane&15)]
__global__ void k_wpack1(const float* __restrict__ W, unsigned short* __restrict__ out) {
    int t = blockIdx.x * blockDim.x + threadIdx.x;  // 0..2047
    if (t >= 2048) return;
    int lane = t & 63;
    int nt = (t >> 6) & 7;
    int kk = t >> 9;
    int n = nt * 16 + (lane & 15);
    int k0 = kk * 32 + (lane >> 4) * 8;
    ushort8v h8;
#pragma unroll
    for (int j = 0; j < 8; ++j) h8[j] = f2b(W[(size_t)(k0 + j) * DIMS + n]);
    *(ushort8v*)&out[(size_t)t * 8] = h8;
}

// ---------------- gather (bf16 rows): agg = \hat{A} @ X ----------------
__global__ __launch_bounds__(256) void k_gather_b(
    const unsigned short* __restrict__ Xb, const float* __restrict__ dinv,
    const int* __restrict__ row_ptr, const int* __restrict__ cnt,
    const int* __restrict__ col, const float* __restrict__ wgt,
    float* __restrict__ agg, int N)
{
    int t = blockIdx.x * blockDim.x + threadIdx.x;
    int node = t >> 5;
    if (node >= N) return;
    int lane = t & 31;

    float ds = dinv[node];
    float w0 = ds * ds;
    ushort4 sv = *(const ushort4*)&Xb[(size_t)node * DIMS + lane * 4];
    float ax = b2f(sv.x) * w0, ay = b2f(sv.y) * w0, az = b2f(sv.z) * w0, aw = b2f(sv.w) * w0;

    int beg = row_ptr[node];
    int m = cnt[node];
    int j = 0;
    for (; j + 1 < m; j += 2) {
        int s0 = col[beg + j], s1 = col[beg + j + 1];
        float wa = wgt[beg + j], wb = wgt[beg + j + 1];
        ushort4 v0 = *(const ushort4*)&Xb[(size_t)s0 * DIMS + lane * 4];
        ushort4 v1 = *(const ushort4*)&Xb[(size_t)s1 * DIMS + lane * 4];
        ax = fmaf(wa, b2f(v0.x), ax); ay = fmaf(wa, b2f(v0.y), ay);
        az = fmaf(wa, b2f(v0.z), az); aw = fmaf(wa, b2f(v0.w), aw);
        ax = fmaf(wb, b2f(v1.x), ax); ay = fmaf(wb, b2f(v1.y), ay);
        az = fmaf(wb, b2f(v1.z), az); aw = fmaf(wb, b2f(v1.w), aw);
    }
    if (j < m) {
        int s0 = col[beg + j];
        float wa = wgt[beg + j];
        ushort4 v0 = *(const ushort4*)&Xb[(size_t)s0 * DIMS + lane * 4];
        ax = fmaf(wa, b2f(v0.x), ax); ay = fmaf(wa, b2f(v0.y), ay);
        az = fmaf(wa, b2f(v0.z), az); aw = fmaf(wa, b2f(v0.w), aw);
    }
    float4 o = {ax, ay, az, aw};
    *(float4*)&agg[(size_t)node * DIMS + lane * 4] = o;
}

// ---------------- MFMA dual-GEMM + coupling, v2 (LDS-staged W) ----------------
// Wpk = [Ws frags 16384 ushorts][Wt frags 16384 ushorts], staged to 64KB LDS.
// s = tanh(A@Ws+bs); t = A@Wt+bt; Out = Xo*exp(s)+t; optional bf16 copy OutB.
// 512 threads = 8 waves x 16 rows = 128-row tile per block. A may alias Out
// (each wave loads its 16 A-rows into regs before the epilogue writes them;
// OOB-clamped duplicate reads only feed fully-discarded output tiles).
__global__ __launch_bounds__(512, 4) void k_mfma_couple2(
    const float* __restrict__ A, const unsigned short* __restrict__ Wpk,
    const float* __restrict__ bs, const float* __restrict__ bt,
    const float* __restrict__ Xo, float* __restrict__ Out,
    unsigned short* OutB, int N, int ntiles)
{
    __shared__ unsigned short lds[32768];  // 64 KB: Ws frags | Wt frags
    for (int i = threadIdx.x; i < 4096; i += 512)
        *(ushort8v*)&lds[(size_t)i * 8] = *(const ushort8v*)&Wpk[(size_t)i * 8];
    __syncthreads();
    const unsigned short* wsf = lds;
    const unsigned short* wtf = lds + 16384;

    const int wave = threadIdx.x >> 6, lane = threadIdx.x & 63;

    for (int tile = blockIdx.x; tile < ntiles; tile += gridDim.x) {
        const int rbase = tile * 128 + wave * 16;

        // ---- A fragments (bf16 single-term) ----
        int arow = rbase + (lane & 15);
        if (arow >= N) arow = N - 1;
        const int acol = (lane >> 4) * 8;
        bf16x8 ahi[4];
#pragma unroll
        for (int kk = 0; kk < 4; ++kk) {
            const float* ap = &A[(size_t)arow * DIMS + kk * 32 + acol];
            float4 a0 = *(const float4*)ap;
            float4 a1 = *(const float4*)(ap + 4);
            bf16x8 h;
            h[0] = (short)f2b(a0.x); h[1] = (short)f2b(a0.y);
            h[2] = (short)f2b(a0.z); h[3] = (short)f2b(a0.w);
            h[4] = (short)f2b(a1.x); h[5] = (short)f2b(a1.y);
            h[6] = (short)f2b(a1.z); h[7] = (short)f2b(a1.w);
            ahi[kk] = h;
        }

        f32x4 acc_s[8], acc_t[8];
#pragma unroll
        for (int nt = 0; nt < 8; ++nt) {
            acc_s[nt] = (f32x4){0.f, 0.f, 0.f, 0.f};
            acc_t[nt] = (f32x4){0.f, 0.f, 0.f, 0.f};
        }

#pragma unroll
        for (int kk = 0; kk < 4; ++kk) {
#pragma unroll
            for (int nt = 0; nt < 8; ++nt) {
                const int fi = ((kk * 8 + nt) * 64 + lane) * 8;
                bf16x8 ws = *(const bf16x8*)&wsf[fi];
                bf16x8 wt = *(const bf16x8*)&wtf[fi];
                acc_s[nt] = __builtin_amdgcn_mfma_f32_16x16x32_bf16(ahi[kk], ws, acc_s[nt], 0, 0, 0);
                acc_t[nt] = __builtin_amdgcn_mfma_f32_16x16x32_bf16(ahi[kk], wt, acc_t[nt], 0, 0, 0);
            }
        }

        // ---- epilogue: C layout col=lane&15, row=(lane>>4)*4+q ----
        const int crow0 = rbase + (lane >> 4) * 4;
        const int ccol = lane & 15;
#pragma unroll
        for (int nt = 0; nt < 8; ++nt) {
            const int cg = nt * 16 + ccol;
            const float bsv = bs[cg], btv = bt[cg];
#pragma unroll
            for (int q = 0; q < 4; ++q) {
                const int rg = crow0 + q;
                if (rg < N) {
                    float s = tanhf(acc_s[nt][q] + bsv);
                    float tt = acc_t[nt][q] + btv;
                    float xo = Xo[(size_t)rg * DIMS + cg];
                    float o = xo * expf(s) + tt;
                    Out[(size_t)rg * DIMS + cg] = o;
                    if (OutB) OutB[(size_t)rg * DIMS + cg] = f2b(o);
                }
            }
        }
    }
}

// ---------------- f32 fallback kernels (round-2 path) ----------------
__global__ __launch_bounds__(256) void k_gather(
    const float4* __restrict__ X4, const float* __restrict__ dinv,
    const int* __restrict__ row_ptr, const int* __restrict__ cnt,
    const int* __restrict__ col, const float* __restrict__ wgt,
    float4* __restrict__ agg4, int N)
{
    int t = blockIdx.x * blockDim.x + threadIdx.x;
    int node = t >> 5;
    if (node >= N) return;
    int lane = t & 31;
    float ds = dinv[node];
    float w0 = ds * ds;
    float4 acc = X4[(size_t)node * 32 + lane];
    acc.x *= w0; acc.y *= w0; acc.z *= w0; acc.w *= w0;
    int beg = row_ptr[node];
    int m = cnt[node];
    for (int j = 0; j < m; ++j) {
        int s0 = col[beg + j];
        float wa = wgt[beg + j];
        float4 v0 = X4[(size_t)s0 * 32 + lane];
        acc.x = fmaf(wa, v0.x, acc.x); acc.y = fmaf(wa, v0.y, acc.y);
        acc.z = fmaf(wa, v0.z, acc.z); acc.w = fmaf(wa, v0.w, acc.w);
    }
    agg4[(size_t)node * 32 + lane] = acc;
}

__global__ __launch_bounds__(256) void k_gemm_couple(
    const float* A, const float* __restrict__ Ws, const float* __restrict__ bs,
    const float* __restrict__ Wt, const float* __restrict__ bt,
    const float* __restrict__ Xo, float* Out, int N)
{
    constexpr int TM = 64, TK = 16;
    __shared__ float As[TK][TM + 4];
    __shared__ float Ss[TK][DIMS];
    __shared__ float St[TK][DIMS];
    const int tid = threadIdx.x;
    const int ty = tid >> 4, tx = tid & 15;
    const int r0 = ty * 4, c0 = tx * 8;
    const int block_row = blockIdx.x * TM;

    float acc_s[4][8], acc_t[4][8];
#pragma unroll
    for (int r = 0; r < 4; ++r)
#pragma unroll
        for (int c = 0; c < 8; ++c) { acc_s[r][c] = 0.f; acc_t[r][c] = 0.f; }

    const int ar = tid >> 2;
    const int aq = tid & 3;
    int arow = block_row + ar;
    if (arow >= N) arow = N - 1;

    for (int k0 = 0; k0 < DIMS; k0 += TK) {
        __syncthreads();
        {
            float4 v = *(const float4*)&A[(size_t)arow * DIMS + k0 + aq * 4];
            As[aq * 4 + 0][ar] = v.x;
            As[aq * 4 + 1][ar] = v.y;
            As[aq * 4 + 2][ar] = v.z;
            As[aq * 4 + 3][ar] = v.w;
        }
#pragma unroll
        for (int i = 0; i < 2; ++i) {
            int idx = tid + i * 256;
            int kk = idx >> 5;
            int j4 = idx & 31;
            *(float4*)&Ss[kk][j4 * 4] = *(const float4*)&Ws[(size_t)(k0 + kk) * DIMS + j4 * 4];
            *(float4*)&St[kk][j4 * 4] = *(const float4*)&Wt[(size_t)(k0 + kk) * DIMS + j4 * 4];
        }
        __syncthreads();
#pragma unroll
        for (int k = 0; k < TK; ++k) {
            float4 av = *(const float4*)&As[k][r0];
            float a[4] = {av.x, av.y, av.z, av.w};
            float ws8[8], wt8[8];
            *(float4*)&ws8[0] = *(const float4*)&Ss[k][c0];
            *(float4*)&ws8[4] = *(const float4*)&Ss[k][c0 + 4];
            *(float4*)&wt8[0] = *(const float4*)&St[k][c0];
            *(float4*)&wt8[4] = *(const float4*)&St[k][c0 + 4];
#pragma unroll
            for (int r = 0; r < 4; ++r)
#pragma unroll
                for (int c = 0; c < 8; ++c) {
                    acc_s[r][c] = fmaf(a[r], ws8[c], acc_s[r][c]);
                    acc_t[r][c] = fmaf(a[r], wt8[c], acc_t[r][c]);
                }
        }
    }

    float bsv[8], btv[8];
    *(float4*)&bsv[0] = *(const float4*)&bs[c0];
    *(float4*)&bsv[4] = *(const float4*)&bs[c0 + 4];
    *(float4*)&btv[0] = *(const float4*)&bt[c0];
    *(float4*)&btv[4] = *(const float4*)&bt[c0 + 4];
#pragma unroll
    for (int r = 0; r < 4; ++r) {
        int row = block_row + r0 + r;
        if (row < N) {
            float xo[8];
            *(float4*)&xo[0] = *(const float4*)&Xo[(size_t)row * DIMS + c0];
            *(float4*)&xo[4] = *(const float4*)&Xo[(size_t)row * DIMS + c0 + 4];
            float o[8];
#pragma unroll
            for (int c = 0; c < 8; ++c) {
                float s = tanhf(acc_s[r][c] + bsv[c]);
                float t = acc_t[r][c] + btv[c];
                o[c] = xo[c] * expf(s) + t;
            }
            *(float4*)&Out[(size_t)row * DIMS + c0] = *(const float4*)&o[0];
            *(float4*)&Out[(size_t)row * DIMS + c0 + 4] = *(const float4*)&o[4];
        }
    }
}

extern "C" void kernel_launch(void* const* d_in, const int* in_sizes, int n_in,
                              void* d_out, int out_size, void* d_ws, size_t ws_size,
                              hipStream_t stream) {
    const float* x_main  = (const float*)d_in[0];
    const float* x_guide = (const float*)d_in[1];
    const int*   ei      = (const int*)d_in[2];
    const float* Ws1 = (const float*)d_in[3];
    const float* bs1 = (const float*)d_in[4];
    const float* Wt1 = (const float*)d_in[5];
    const float* bt1 = (const float*)d_in[6];
    const float* Ws2 = (const float*)d_in[7];
    const float* bs2 = (const float*)d_in[8];
    const float* Wt2 = (const float*)d_in[9];
    const float* bt2 = (const float*)d_in[10];

    const int N = in_sizes[0] / DIMS;
    const int E = in_sizes[2] / 2;
    const int* src = ei;
    const int* dst = ei + E;

    float* out_main  = (float*)d_out;
    float* out_guide = out_main + (size_t)N * DIMS;
    float* agg = out_guide;  // scratch aliasing second output (written last)

    // ---- ws layout ----
    char* w = (char*)d_ws;
    size_t off = 0;
    auto alloc = [&](size_t bytes) { size_t o = off; off = (off + bytes + 15) & ~(size_t)15; return o; };
    int*   cnt     = (int*)(w + alloc((size_t)N * 4));
    int*   row_ptr = (int*)(w + alloc((size_t)N * 4));
    int*   cursor  = (int*)(w + alloc((size_t)N * 4));
    int*   bump    = (int*)(w + alloc(64));
    float* dinv    = (float*)(w + alloc((size_t)N * 4));
    int*   col     = (int*)(w + alloc((size_t)E * 4));
    float* wgt     = (float*)(w + alloc((size_t)E * 4));
    unsigned short* xb  = (unsigned short*)(w + alloc((size_t)N * DIMS * 2));
    unsigned short* wpk = (unsigned short*)(w + alloc((size_t)4 * 16384 * 2));
    size_t needed3 = off;

    const int gather_grid = (N * 32 + 255) / 256;
    const int gemm_grid   = (N + 63) / 64;
    const int ntiles      = (N + 127) / 128;

    // ---- CSR build (shared by both paths) ----
    hipMemsetAsync(cnt, 0, ((char*)(bump + 16)) - (char*)cnt, stream);
    k_count<<<(E + 255) / 256, 256, 0, stream>>>(dst, cnt, E);
    k_dinv2<<<(N + 255) / 256, 256, 0, stream>>>(cnt, dinv, N);
    k_alloc<<<(N + 255) / 256, 256, 0, stream>>>(cnt, row_ptr, bump, N);
    k_fill<<<(E + 255) / 256, 256, 0, stream>>>(src, dst, row_ptr, cursor, dinv, col, wgt, E);

    if (ws_size >= needed3) {
        unsigned short* W1pk = wpk;              // [Ws1 | Wt1] frags
        unsigned short* W2pk = wpk + 2 * 16384;  // [Ws2 | Wt2] frags
        k_wpack1<<<8, 256, 0, stream>>>(Ws1, W1pk);
        k_wpack1<<<8, 256, 0, stream>>>(Wt1, W1pk + 16384);
        k_wpack1<<<8, 256, 0, stream>>>(Ws2, W2pk);
        k_wpack1<<<8, 256, 0, stream>>>(Wt2, W2pk + 16384);

        const int n8 = N * DIMS / 8;
        k_cast<<<(n8 + 255) / 256, 256, 0, stream>>>(x_guide, xb, n8);

        // ---- stage 1 ----
        k_gather_b<<<gather_grid, 256, 0, stream>>>(xb, dinv, row_ptr, cnt, col, wgt, agg, N);
        k_mfma_couple2<<<ntiles, 512, 0, stream>>>(agg, W1pk, bs1, bt1, x_main, out_main, xb, N, ntiles);
        // ---- stage 2 ----
        k_gather_b<<<gather_grid, 256, 0, stream>>>(xb, dinv, row_ptr, cnt, col, wgt, agg, N);
        k_mfma_couple2<<<ntiles, 512, 0, stream>>>(agg, W2pk, bs2, bt2, x_guide, out_guide, nullptr, N, ntiles);
    } else {
        // ---- fallback: round-2 f32 path ----
        k_gather<<<gather_grid, 256, 0, stream>>>((const float4*)x_guide, dinv, row_ptr, cnt,
                                                  col, wgt, (float4*)agg, N);
        k_gemm_couple<<<gemm_grid, 256, 0, stream>>>(agg, Ws1, bs1, Wt1, bt1, x_main, out_main, N);
        k_gather<<<gather_grid, 256, 0, stream>>>((const float4*)out_main, dinv, row_ptr, cnt,
                                                  col, wgt, (float4*)agg, N);
        k_gemm_couple<<<gemm_grid, 256, 0, stream>>>(agg, Ws2, bs2, Wt2, bt2, x_guide, out_guide, N);
    }
}

// Round 5
// 492.399 us; speedup vs baseline: 1.8074x; 1.8074x over previous
//
#include <hip/hip_runtime.h>
#include <cstdint>
#include <cstddef>

constexpr int DIMS = 128;

typedef __attribute__((ext_vector_type(8))) short bf16x8;
typedef __attribute__((ext_vector_type(8))) unsigned short ushort8v;
typedef __attribute__((ext_vector_type(4))) float f32x4;

__device__ __forceinline__ unsigned short f2b(float f) {
    uint32_t u = __builtin_bit_cast(uint32_t, f);
    uint32_t r = (u + 0x7FFFu + ((u >> 16) & 1u)) >> 16;
    return (unsigned short)r;
}
__device__ __forceinline__ float b2f(unsigned short h) {
    uint32_t u = ((uint32_t)h) << 16;
    return __builtin_bit_cast(float, u);
}

// ---------------- degree ----------------
__global__ void k_count(const int* __restrict__ dst, int* __restrict__ cnt, int E) {
    int e = blockIdx.x * blockDim.x + threadIdx.x;
    if (e < E) atomicAdd(&cnt[dst[e]], 1);
}

__global__ void k_dinv2(const int* __restrict__ cnt, float* __restrict__ dinv, int N) {
    int i = blockIdx.x * blockDim.x + threadIdx.x;
    if (i < N) dinv[i] = rsqrtf((float)(cnt[i] + 1));
}

// bump-allocated CSR row offsets (buckets need not be ordered)
__global__ void k_alloc(const int* __restrict__ cnt, int* __restrict__ row_ptr,
                        int* __restrict__ bump, int N) {
    int i = blockIdx.x * blockDim.x + threadIdx.x;
    int lane = threadIdx.x & 63;
    int v = (i < N) ? cnt[i] : 0;
    int x = v;
#pragma unroll
    for (int d = 1; d < 64; d <<= 1) {
        int y = __shfl_up(x, d);
        if (lane >= d) x += y;
    }
    int total = __shfl(x, 63);
    int base = 0;
    if (lane == 0) base = atomicAdd(bump, total);
    base = __shfl(base, 0);
    if (i < N) row_ptr[i] = base + x - v;
}

// bucket fill: col only (weights recomputed in gather from dinv table)
__global__ void k_fill2(const int* __restrict__ src, const int* __restrict__ dst,
                        const int* __restrict__ row_ptr, int* __restrict__ cursor,
                        int* __restrict__ col, int E) {
    int e = blockIdx.x * blockDim.x + threadIdx.x;
    if (e >= E) return;
    int s = src[e], d = dst[e];
    int pos = row_ptr[d] + atomicAdd(&cursor[d], 1);
    col[pos] = s;
}

// ---------------- f32 -> bf16 row cast (8 elems/thread) ----------------
__global__ void k_cast(const float* __restrict__ X, unsigned short* __restrict__ Y, int n8) {
    int i = blockIdx.x * blockDim.x + threadIdx.x;
    if (i >= n8) return;
    const float4* p = (const float4*)X + (size_t)i * 2;
    float4 a = p[0], b = p[1];
    ushort8v o;
    o[0] = f2b(a.x); o[1] = f2b(a.y); o[2] = f2b(a.z); o[3] = f2b(a.w);
    o[4] = f2b(b.x); o[5] = f2b(b.y); o[6] = f2b(b.z); o[7] = f2b(b.w);
    *(ushort8v*)&Y[(size_t)i * 8] = o;
}

// ---------------- W pack: f32 [128][128] -> bf16 fragment layout ----------------
// t = (kk*8+nt)*64+lane ; elem j = W[kk*32+(lane>>4)*8+j][nt*16+(lane&15)]
// Used as the MFMA *A* operand (= W^T tile): lane&15 -> n, (lane>>4)*8+j -> k.
__global__ void k_wpack1(const float* __restrict__ W, unsigned short* __restrict__ out) {
    int t = blockIdx.x * blockDim.x + threadIdx.x;  // 0..2047
    if (t >= 2048) return;
    int lane = t & 63;
    int nt = (t >> 6) & 7;
    int kk = t >> 9;
    int n = nt * 16 + (lane & 15);
    int k0 = kk * 32 + (lane >> 4) * 8;
    ushort8v h8;
#pragma unroll
    for (int j = 0; j < 8; ++j) h8[j] = f2b(W[(size_t)(k0 + j) * DIMS + n]);
    *(ushort8v*)&out[(size_t)t * 8] = h8;
}

// ---------------- gather (bf16 in, bf16 out): aggb = bf16(\hat{A} @ X) ----------------
__global__ __launch_bounds__(256) void k_gather_b2(
    const unsigned short* __restrict__ Xb, const float* __restrict__ dinv,
    const int* __restrict__ row_ptr, const int* __restrict__ cnt,
    const int* __restrict__ col, unsigned short* __restrict__ aggb, int N)
{
    int t = blockIdx.x * blockDim.x + threadIdx.x;
    int node = t >> 5;
    if (node >= N) return;
    int lane = t & 31;

    float ds = dinv[node];
    float w0 = ds * ds;
    ushort4 sv = *(const ushort4*)&Xb[(size_t)node * DIMS + lane * 4];
    float ax = b2f(sv.x) * w0, ay = b2f(sv.y) * w0, az = b2f(sv.z) * w0, aw = b2f(sv.w) * w0;

    int beg = row_ptr[node];
    int m = cnt[node];
    int j = 0;
    for (; j + 1 < m; j += 2) {
        int s0 = col[beg + j], s1 = col[beg + j + 1];
        float wa = ds * dinv[s0], wb = ds * dinv[s1];
        ushort4 v0 = *(const ushort4*)&Xb[(size_t)s0 * DIMS + lane * 4];
        ushort4 v1 = *(const ushort4*)&Xb[(size_t)s1 * DIMS + lane * 4];
        ax = fmaf(wa, b2f(v0.x), ax); ay = fmaf(wa, b2f(v0.y), ay);
        az = fmaf(wa, b2f(v0.z), az); aw = fmaf(wa, b2f(v0.w), aw);
        ax = fmaf(wb, b2f(v1.x), ax); ay = fmaf(wb, b2f(v1.y), ay);
        az = fmaf(wb, b2f(v1.z), az); aw = fmaf(wb, b2f(v1.w), aw);
    }
    if (j < m) {
        int s0 = col[beg + j];
        float wa = ds * dinv[s0];
        ushort4 v0 = *(const ushort4*)&Xb[(size_t)s0 * DIMS + lane * 4];
        ax = fmaf(wa, b2f(v0.x), ax); ay = fmaf(wa, b2f(v0.y), ay);
        az = fmaf(wa, b2f(v0.z), az); aw = fmaf(wa, b2f(v0.w), aw);
    }
    ushort4 o;
    o.x = f2b(ax); o.y = f2b(ay); o.z = f2b(az); o.w = f2b(aw);
    *(ushort4*)&aggb[(size_t)node * DIMS + lane * 4] = o;
}

// ---------------- MFMA dual-GEMM + coupling, v3 ----------------
// Computes (A@W)^T via mfma(Wfrag, Afrag): lane holds one output ROW (lane&15)
// and 4 consecutive output cols per acc reg -> float4 epilogue I/O.
// A is bf16 (aggb). 256 thr = 4 waves x 16 rows = 64-row tile; grid-stride.
__global__ __launch_bounds__(256) void k_mfma_couple3(
    const unsigned short* __restrict__ Ab, const unsigned short* __restrict__ Wpk,
    const float* __restrict__ bs, const float* __restrict__ bt,
    const float* __restrict__ Xo, float* __restrict__ Out,
    unsigned short* OutB, int N, int ntiles)
{
    __shared__ unsigned short lds[32768];  // 64 KB: Ws frags | Wt frags
    for (int i = threadIdx.x; i < 4096; i += 256)
        *(ushort8v*)&lds[(size_t)i * 8] = *(const ushort8v*)&Wpk[(size_t)i * 8];
    __syncthreads();
    const unsigned short* wsf = lds;
    const unsigned short* wtf = lds + 16384;

    const int wave = threadIdx.x >> 6, lane = threadIdx.x & 63;
    const int rsub = lane & 15;          // output row within wave tile
    const int ksub = (lane >> 4) * 8;    // k-offset within 32-chunk (A-frag)
    const int csub = (lane >> 4) * 4;    // col offset within 16-chunk (epilogue)

    for (int tile = blockIdx.x; tile < ntiles; tile += gridDim.x) {
        const int m = tile * 64 + wave * 16 + rsub;
        const int mld = (m < N) ? m : (N - 1);   // clamped for loads
        const bool valid = (m < N);

        // ---- A fragments (bf16 rows, direct 16B loads) ----
        bf16x8 af[4];
#pragma unroll
        for (int kk = 0; kk < 4; ++kk)
            af[kk] = *(const bf16x8*)&Ab[(size_t)mld * DIMS + kk * 32 + ksub];

        f32x4 acc_s[8], acc_t[8];
#pragma unroll
        for (int nt = 0; nt < 8; ++nt) {
            acc_s[nt] = (f32x4){0.f, 0.f, 0.f, 0.f};
            acc_t[nt] = (f32x4){0.f, 0.f, 0.f, 0.f};
        }

#pragma unroll
        for (int kk = 0; kk < 4; ++kk) {
#pragma unroll
            for (int nt = 0; nt < 8; ++nt) {
                const int fi = ((kk * 8 + nt) * 64 + lane) * 8;
                bf16x8 ws = *(const bf16x8*)&wsf[fi];
                bf16x8 wt = *(const bf16x8*)&wtf[fi];
                // swapped operands: D = W^T tile @ A^T tile = (A@W)^T chunk
                acc_s[nt] = __builtin_amdgcn_mfma_f32_16x16x32_bf16(ws, af[kk], acc_s[nt], 0, 0, 0);
                acc_t[nt] = __builtin_amdgcn_mfma_f32_16x16x32_bf16(wt, af[kk], acc_t[nt], 0, 0, 0);
            }
        }

        // ---- epilogue: lane owns row m, cols nt*16+csub .. +3 ----
        if (valid) {
#pragma unroll
            for (int nt = 0; nt < 8; ++nt) {
                const int c4 = nt * 16 + csub;
                float4 bsv = *(const float4*)&bs[c4];
                float4 btv = *(const float4*)&bt[c4];
                float4 xo  = *(const float4*)&Xo[(size_t)m * DIMS + c4];
                float4 o;
                o.x = xo.x * expf(tanhf(acc_s[nt][0] + bsv.x)) + (acc_t[nt][0] + btv.x);
                o.y = xo.y * expf(tanhf(acc_s[nt][1] + bsv.y)) + (acc_t[nt][1] + btv.y);
                o.z = xo.z * expf(tanhf(acc_s[nt][2] + bsv.z)) + (acc_t[nt][2] + btv.z);
                o.w = xo.w * expf(tanhf(acc_s[nt][3] + bsv.w)) + (acc_t[nt][3] + btv.w);
                *(float4*)&Out[(size_t)m * DIMS + c4] = o;
                if (OutB) {
                    ushort4 ob;
                    ob.x = f2b(o.x); ob.y = f2b(o.y); ob.z = f2b(o.z); ob.w = f2b(o.w);
                    *(ushort4*)&OutB[(size_t)m * DIMS + c4] = ob;
                }
            }
        }
    }
}

// ---------------- f32 fallback kernels (round-2 path) ----------------
__global__ void k_fill(const int* __restrict__ src, const int* __restrict__ dst,
                       const int* __restrict__ row_ptr, int* __restrict__ cursor,
                       const float* __restrict__ dinv,
                       int* __restrict__ col, float* __restrict__ wgt, int E) {
    int e = blockIdx.x * blockDim.x + threadIdx.x;
    if (e >= E) return;
    int s = src[e], d = dst[e];
    int pos = row_ptr[d] + atomicAdd(&cursor[d], 1);
    col[pos] = s;
    wgt[pos] = dinv[s] * dinv[d];
}

__global__ __launch_bounds__(256) void k_gather(
    const float4* __restrict__ X4, const float* __restrict__ dinv,
    const int* __restrict__ row_ptr, const int* __restrict__ cnt,
    const int* __restrict__ col, const float* __restrict__ wgt,
    float4* __restrict__ agg4, int N)
{
    int t = blockIdx.x * blockDim.x + threadIdx.x;
    int node = t >> 5;
    if (node >= N) return;
    int lane = t & 31;
    float ds = dinv[node];
    float w0 = ds * ds;
    float4 acc = X4[(size_t)node * 32 + lane];
    acc.x *= w0; acc.y *= w0; acc.z *= w0; acc.w *= w0;
    int beg = row_ptr[node];
    int m = cnt[node];
    for (int j = 0; j < m; ++j) {
        int s0 = col[beg + j];
        float wa = wgt[beg + j];
        float4 v0 = X4[(size_t)s0 * 32 + lane];
        acc.x = fmaf(wa, v0.x, acc.x); acc.y = fmaf(wa, v0.y, acc.y);
        acc.z = fmaf(wa, v0.z, acc.z); acc.w = fmaf(wa, v0.w, acc.w);
    }
    agg4[(size_t)node * 32 + lane] = acc;
}

__global__ __launch_bounds__(256) void k_gemm_couple(
    const float* A, const float* __restrict__ Ws, const float* __restrict__ bs,
    const float* __restrict__ Wt, const float* __restrict__ bt,
    const float* __restrict__ Xo, float* Out, int N)
{
    constexpr int TM = 64, TK = 16;
    __shared__ float As[TK][TM + 4];
    __shared__ float Ss[TK][DIMS];
    __shared__ float St[TK][DIMS];
    const int tid = threadIdx.x;
    const int ty = tid >> 4, tx = tid & 15;
    const int r0 = ty * 4, c0 = tx * 8;
    const int block_row = blockIdx.x * TM;

    float acc_s[4][8], acc_t[4][8];
#pragma unroll
    for (int r = 0; r < 4; ++r)
#pragma unroll
        for (int c = 0; c < 8; ++c) { acc_s[r][c] = 0.f; acc_t[r][c] = 0.f; }

    const int ar = tid >> 2;
    const int aq = tid & 3;
    int arow = block_row + ar;
    if (arow >= N) arow = N - 1;

    for (int k0 = 0; k0 < DIMS; k0 += TK) {
        __syncthreads();
        {
            float4 v = *(const float4*)&A[(size_t)arow * DIMS + k0 + aq * 4];
            As[aq * 4 + 0][ar] = v.x;
            As[aq * 4 + 1][ar] = v.y;
            As[aq * 4 + 2][ar] = v.z;
            As[aq * 4 + 3][ar] = v.w;
        }
#pragma unroll
        for (int i = 0; i < 2; ++i) {
            int idx = tid + i * 256;
            int kk = idx >> 5;
            int j4 = idx & 31;
            *(float4*)&Ss[kk][j4 * 4] = *(const float4*)&Ws[(size_t)(k0 + kk) * DIMS + j4 * 4];
            *(float4*)&St[kk][j4 * 4] = *(const float4*)&Wt[(size_t)(k0 + kk) * DIMS + j4 * 4];
        }
        __syncthreads();
#pragma unroll
        for (int k = 0; k < TK; ++k) {
            float4 av = *(const float4*)&As[k][r0];
            float a[4] = {av.x, av.y, av.z, av.w};
            float ws8[8], wt8[8];
            *(float4*)&ws8[0] = *(const float4*)&Ss[k][c0];
            *(float4*)&ws8[4] = *(const float4*)&Ss[k][c0 + 4];
            *(float4*)&wt8[0] = *(const float4*)&St[k][c0];
            *(float4*)&wt8[4] = *(const float4*)&St[k][c0 + 4];
#pragma unroll
            for (int r = 0; r < 4; ++r)
#pragma unroll
                for (int c = 0; c < 8; ++c) {
                    acc_s[r][c] = fmaf(a[r], ws8[c], acc_s[r][c]);
                    acc_t[r][c] = fmaf(a[r], wt8[c], acc_t[r][c]);
                }
        }
    }

    float bsv[8], btv[8];
    *(float4*)&bsv[0] = *(const float4*)&bs[c0];
    *(float4*)&bsv[4] = *(const float4*)&bs[c0 + 4];
    *(float4*)&btv[0] = *(const float4*)&bt[c0];
    *(float4*)&btv[4] = *(const float4*)&bt[c0 + 4];
#pragma unroll
    for (int r = 0; r < 4; ++r) {
        int row = block_row + r0 + r;
        if (row < N) {
            float xo[8];
            *(float4*)&xo[0] = *(const float4*)&Xo[(size_t)row * DIMS + c0];
            *(float4*)&xo[4] = *(const float4*)&Xo[(size_t)row * DIMS + c0 + 4];
            float o[8];
#pragma unroll
            for (int c = 0; c < 8; ++c) {
                float s = tanhf(acc_s[r][c] + bsv[c]);
                float t = acc_t[r][c] + btv[c];
                o[c] = xo[c] * expf(s) + t;
            }
            *(float4*)&Out[(size_t)row * DIMS + c0] = *(const float4*)&o[0];
            *(float4*)&Out[(size_t)row * DIMS + c0 + 4] = *(const float4*)&o[4];
        }
    }
}

extern "C" void kernel_launch(void* const* d_in, const int* in_sizes, int n_in,
                              void* d_out, int out_size, void* d_ws, size_t ws_size,
                              hipStream_t stream) {
    const float* x_main  = (const float*)d_in[0];
    const float* x_guide = (const float*)d_in[1];
    const int*   ei      = (const int*)d_in[2];
    const float* Ws1 = (const float*)d_in[3];
    const float* bs1 = (const float*)d_in[4];
    const float* Wt1 = (const float*)d_in[5];
    const float* bt1 = (const float*)d_in[6];
    const float* Ws2 = (const float*)d_in[7];
    const float* bs2 = (const float*)d_in[8];
    const float* Wt2 = (const float*)d_in[9];
    const float* bt2 = (const float*)d_in[10];

    const int N = in_sizes[0] / DIMS;
    const int E = in_sizes[2] / 2;
    const int* src = ei;
    const int* dst = ei + E;

    float* out_main  = (float*)d_out;
    float* out_guide = out_main + (size_t)N * DIMS;

    // ---- ws layout ----
    char* w = (char*)d_ws;
    size_t off = 0;
    auto alloc = [&](size_t bytes) { size_t o = off; off = (off + bytes + 15) & ~(size_t)15; return o; };
    int*   cnt     = (int*)(w + alloc((size_t)N * 4));
    int*   row_ptr = (int*)(w + alloc((size_t)N * 4));
    int*   cursor  = (int*)(w + alloc((size_t)N * 4));
    int*   bump    = (int*)(w + alloc(64));
    float* dinv    = (float*)(w + alloc((size_t)N * 4));
    int*   col     = (int*)(w + alloc((size_t)E * 4));
    size_t base_end = off;
    // MFMA path extras
    unsigned short* xb   = (unsigned short*)(w + alloc((size_t)N * DIMS * 2));
    unsigned short* aggb = (unsigned short*)(w + alloc((size_t)N * DIMS * 2));
    unsigned short* wpk  = (unsigned short*)(w + alloc((size_t)4 * 16384 * 2));
    size_t needed_mfma = off;
    // f32 fallback extras (overlap the MFMA region)
    float* wgt = (float*)(w + base_end);
    size_t needed_f32 = base_end + (size_t)E * 4;

    const int gather_grid = (N * 32 + 255) / 256;
    const int gemm_grid   = (N + 63) / 64;
    const int ntiles64    = (N + 63) / 64;
    const int mfma_grid   = (ntiles64 < 512) ? ntiles64 : 512;

    // ---- CSR skeleton (shared) ----
    hipMemsetAsync(cnt, 0, ((char*)(bump + 16)) - (char*)cnt, stream);
    k_count<<<(E + 255) / 256, 256, 0, stream>>>(dst, cnt, E);
    k_dinv2<<<(N + 255) / 256, 256, 0, stream>>>(cnt, dinv, N);
    k_alloc<<<(N + 255) / 256, 256, 0, stream>>>(cnt, row_ptr, bump, N);

    if (ws_size >= needed_mfma) {
        k_fill2<<<(E + 255) / 256, 256, 0, stream>>>(src, dst, row_ptr, cursor, col, E);

        unsigned short* W1pk = wpk;              // [Ws1 | Wt1]
        unsigned short* W2pk = wpk + 2 * 16384;  // [Ws2 | Wt2]
        k_wpack1<<<8, 256, 0, stream>>>(Ws1, W1pk);
        k_wpack1<<<8, 256, 0, stream>>>(Wt1, W1pk + 16384);
        k_wpack1<<<8, 256, 0, stream>>>(Ws2, W2pk);
        k_wpack1<<<8, 256, 0, stream>>>(Wt2, W2pk + 16384);

        const int n8 = N * DIMS / 8;
        k_cast<<<(n8 + 255) / 256, 256, 0, stream>>>(x_guide, xb, n8);

        // ---- stage 1: aggb = bf16(Â@x_guide); out_main = x_main*exp(s1)+t1 ----
        k_gather_b2<<<gather_grid, 256, 0, stream>>>(xb, dinv, row_ptr, cnt, col, aggb, N);
        k_mfma_couple3<<<mfma_grid, 256, 0, stream>>>(aggb, W1pk, bs1, bt1, x_main,
                                                      out_main, xb, N, ntiles64);
        // ---- stage 2: aggb = bf16(Â@out_main); out_guide = x_guide*exp(s2)+t2 ----
        k_gather_b2<<<gather_grid, 256, 0, stream>>>(xb, dinv, row_ptr, cnt, col, aggb, N);
        k_mfma_couple3<<<mfma_grid, 256, 0, stream>>>(aggb, W2pk, bs2, bt2, x_guide,
                                                      out_guide, nullptr, N, ntiles64);
    } else if (ws_size >= needed_f32) {
        // ---- fallback: round-2 f32 path (agg aliases out_guide) ----
        float* agg = out_guide;
        k_fill<<<(E + 255) / 256, 256, 0, stream>>>(src, dst, row_ptr, cursor, dinv, col, wgt, E);
        k_gather<<<gather_grid, 256, 0, stream>>>((const float4*)x_guide, dinv, row_ptr, cnt,
                                                  col, wgt, (float4*)agg, N);
        k_gemm_couple<<<gemm_grid, 256, 0, stream>>>(agg, Ws1, bs1, Wt1, bt1, x_main, out_main, N);
        k_gather<<<gather_grid, 256, 0, stream>>>((const float4*)out_main, dinv, row_ptr, cnt,
                                                  col, wgt, (float4*)agg, N);
        k_gemm_couple<<<gemm_grid, 256, 0, stream>>>(agg, Ws2, bs2, Wt2, bt2, x_guide, out_guide, N);
    }
}

// Round 6
// 437.354 us; speedup vs baseline: 2.0348x; 1.1259x over previous
//
#include <hip/hip_runtime.h>
#include <cstdint>
#include <cstddef>

constexpr int DIMS = 128;

typedef __attribute__((ext_vector_type(8))) short bf16x8;
typedef __attribute__((ext_vector_type(8))) unsigned short ushort8v;
typedef __attribute__((ext_vector_type(4))) float f32x4;

__device__ __forceinline__ unsigned short f2b(float f) {
    uint32_t u = __builtin_bit_cast(uint32_t, f);
    uint32_t r = (u + 0x7FFFu + ((u >> 16) & 1u)) >> 16;
    return (unsigned short)r;
}
__device__ __forceinline__ float b2f(unsigned short h) {
    uint32_t u = ((uint32_t)h) << 16;
    return __builtin_bit_cast(float, u);
}

// ---------------- degree + per-edge slot (atomic return = slot index) ----------------
__global__ void k_count_slot(const int* __restrict__ dst, int* __restrict__ cnt,
                             int* __restrict__ slot, int E) {
    int e = blockIdx.x * blockDim.x + threadIdx.x;
    if (e < E) slot[e] = atomicAdd(&cnt[dst[e]], 1);
}

__global__ void k_dinv2(const int* __restrict__ cnt, float* __restrict__ dinv, int N) {
    int i = blockIdx.x * blockDim.x + threadIdx.x;
    if (i < N) dinv[i] = rsqrtf((float)(cnt[i] + 1));
}

// bump-allocated CSR row offsets (buckets need not be ordered)
__global__ void k_alloc(const int* __restrict__ cnt, int* __restrict__ row_ptr,
                        int* __restrict__ bump, int N) {
    int i = blockIdx.x * blockDim.x + threadIdx.x;
    int lane = threadIdx.x & 63;
    int v = (i < N) ? cnt[i] : 0;
    int x = v;
#pragma unroll
    for (int d = 1; d < 64; d <<= 1) {
        int y = __shfl_up(x, d);
        if (lane >= d) x += y;
    }
    int total = __shfl(x, 63);
    int base = 0;
    if (lane == 0) base = atomicAdd(bump, total);
    base = __shfl(base, 0);
    if (i < N) row_ptr[i] = base + x - v;
}

// atomic-free bucket fill: pos known from (row_ptr, slot)
__global__ void k_fill3(const int* __restrict__ src, const int* __restrict__ dst,
                        const int* __restrict__ row_ptr, const int* __restrict__ slot,
                        int* __restrict__ col, int E) {
    int e = blockIdx.x * blockDim.x + threadIdx.x;
    if (e >= E) return;
    col[row_ptr[dst[e]] + slot[e]] = src[e];
}

// ---------------- f32 -> bf16 row cast (8 elems/thread) ----------------
__global__ void k_cast(const float* __restrict__ X, unsigned short* __restrict__ Y, int n8) {
    int i = blockIdx.x * blockDim.x + threadIdx.x;
    if (i >= n8) return;
    const float4* p = (const float4*)X + (size_t)i * 2;
    float4 a = p[0], b = p[1];
    ushort8v o;
    o[0] = f2b(a.x); o[1] = f2b(a.y); o[2] = f2b(a.z); o[3] = f2b(a.w);
    o[4] = f2b(b.x); o[5] = f2b(b.y); o[6] = f2b(b.z); o[7] = f2b(b.w);
    *(ushort8v*)&Y[(size_t)i * 8] = o;
}

// ---------------- W pack: f32 [128][128] -> bf16 fragment layout ----------------
// t = (kk*8+nt)*64+lane ; elem j = W[kk*32+(lane>>4)*8+j][nt*16+(lane&15)]
__global__ void k_wpack1(const float* __restrict__ W, unsigned short* __restrict__ out) {
    int t = blockIdx.x * blockDim.x + threadIdx.x;  // 0..2047
    if (t >= 2048) return;
    int lane = t & 63;
    int nt = (t >> 6) & 7;
    int kk = t >> 9;
    int n = nt * 16 + (lane & 15);
    int k0 = kk * 32 + (lane >> 4) * 8;
    ushort8v h8;
#pragma unroll
    for (int j = 0; j < 8; ++j) h8[j] = f2b(W[(size_t)(k0 + j) * DIMS + n]);
    *(ushort8v*)&out[(size_t)t * 8] = h8;
}

// ---------------- gather (bf16 in/out), 16 lanes/node, 16B loads ----------------
__global__ __launch_bounds__(256) void k_gather_b3(
    const unsigned short* __restrict__ Xb, const float* __restrict__ dinv,
    const int* __restrict__ row_ptr, const int* __restrict__ cnt,
    const int* __restrict__ col, unsigned short* __restrict__ aggb, int N)
{
    int t = blockIdx.x * blockDim.x + threadIdx.x;
    int node = t >> 4;
    if (node >= N) return;
    const size_t base = (size_t)(t & 15) * 8;

    float ds = dinv[node];
    float w0 = ds * ds;
    ushort8v sv = *(const ushort8v*)&Xb[(size_t)node * DIMS + base];
    float acc[8];
#pragma unroll
    for (int q = 0; q < 8; ++q) acc[q] = b2f(sv[q]) * w0;

    int beg = row_ptr[node];
    int m = cnt[node];
    int j = 0;
    for (; j + 1 < m; j += 2) {               // dual-stream ILP
        int s0 = col[beg + j], s1 = col[beg + j + 1];
        float wa = ds * dinv[s0], wb = ds * dinv[s1];
        ushort8v v0 = *(const ushort8v*)&Xb[(size_t)s0 * DIMS + base];
        ushort8v v1 = *(const ushort8v*)&Xb[(size_t)s1 * DIMS + base];
#pragma unroll
        for (int q = 0; q < 8; ++q) acc[q] = fmaf(wa, b2f(v0[q]), acc[q]);
#pragma unroll
        for (int q = 0; q < 8; ++q) acc[q] = fmaf(wb, b2f(v1[q]), acc[q]);
    }
    if (j < m) {
        int s0 = col[beg + j];
        float wa = ds * dinv[s0];
        ushort8v v0 = *(const ushort8v*)&Xb[(size_t)s0 * DIMS + base];
#pragma unroll
        for (int q = 0; q < 8; ++q) acc[q] = fmaf(wa, b2f(v0[q]), acc[q]);
    }
    ushort8v o;
#pragma unroll
    for (int q = 0; q < 8; ++q) o[q] = f2b(acc[q]);
    *(ushort8v*)&aggb[(size_t)node * DIMS + base] = o;
}

// ---------------- MFMA dual-GEMM + coupling, v3 (unchanged from round 5) ----------------
__global__ __launch_bounds__(256) void k_mfma_couple3(
    const unsigned short* __restrict__ Ab, const unsigned short* __restrict__ Wpk,
    const float* __restrict__ bs, const float* __restrict__ bt,
    const float* __restrict__ Xo, float* __restrict__ Out,
    unsigned short* OutB, int N, int ntiles)
{
    __shared__ unsigned short lds[32768];  // 64 KB: Ws frags | Wt frags
    for (int i = threadIdx.x; i < 4096; i += 256)
        *(ushort8v*)&lds[(size_t)i * 8] = *(const ushort8v*)&Wpk[(size_t)i * 8];
    __syncthreads();
    const unsigned short* wsf = lds;
    const unsigned short* wtf = lds + 16384;

    const int wave = threadIdx.x >> 6, lane = threadIdx.x & 63;
    const int rsub = lane & 15;
    const int ksub = (lane >> 4) * 8;
    const int csub = (lane >> 4) * 4;

    for (int tile = blockIdx.x; tile < ntiles; tile += gridDim.x) {
        const int m = tile * 64 + wave * 16 + rsub;
        const int mld = (m < N) ? m : (N - 1);
        const bool valid = (m < N);

        bf16x8 af[4];
#pragma unroll
        for (int kk = 0; kk < 4; ++kk)
            af[kk] = *(const bf16x8*)&Ab[(size_t)mld * DIMS + kk * 32 + ksub];

        f32x4 acc_s[8], acc_t[8];
#pragma unroll
        for (int nt = 0; nt < 8; ++nt) {
            acc_s[nt] = (f32x4){0.f, 0.f, 0.f, 0.f};
            acc_t[nt] = (f32x4){0.f, 0.f, 0.f, 0.f};
        }

#pragma unroll
        for (int kk = 0; kk < 4; ++kk) {
#pragma unroll
            for (int nt = 0; nt < 8; ++nt) {
                const int fi = ((kk * 8 + nt) * 64 + lane) * 8;
                bf16x8 ws = *(const bf16x8*)&wsf[fi];
                bf16x8 wt = *(const bf16x8*)&wtf[fi];
                acc_s[nt] = __builtin_amdgcn_mfma_f32_16x16x32_bf16(ws, af[kk], acc_s[nt], 0, 0, 0);
                acc_t[nt] = __builtin_amdgcn_mfma_f32_16x16x32_bf16(wt, af[kk], acc_t[nt], 0, 0, 0);
            }
        }

        if (valid) {
#pragma unroll
            for (int nt = 0; nt < 8; ++nt) {
                const int c4 = nt * 16 + csub;
                float4 bsv = *(const float4*)&bs[c4];
                float4 btv = *(const float4*)&bt[c4];
                float4 xo  = *(const float4*)&Xo[(size_t)m * DIMS + c4];
                float4 o;
                o.x = xo.x * expf(tanhf(acc_s[nt][0] + bsv.x)) + (acc_t[nt][0] + btv.x);
                o.y = xo.y * expf(tanhf(acc_s[nt][1] + bsv.y)) + (acc_t[nt][1] + btv.y);
                o.z = xo.z * expf(tanhf(acc_s[nt][2] + bsv.z)) + (acc_t[nt][2] + btv.z);
                o.w = xo.w * expf(tanhf(acc_s[nt][3] + bsv.w)) + (acc_t[nt][3] + btv.w);
                *(float4*)&Out[(size_t)m * DIMS + c4] = o;
                if (OutB) {
                    ushort4 ob;
                    ob.x = f2b(o.x); ob.y = f2b(o.y); ob.z = f2b(o.z); ob.w = f2b(o.w);
                    *(ushort4*)&OutB[(size_t)m * DIMS + c4] = ob;
                }
            }
        }
    }
}

// ---------------- f32 fallback kernels (round-2 path) ----------------
__global__ void k_fill(const int* __restrict__ src, const int* __restrict__ dst,
                       const int* __restrict__ row_ptr, int* __restrict__ cursor,
                       const float* __restrict__ dinv,
                       int* __restrict__ col, float* __restrict__ wgt, int E) {
    int e = blockIdx.x * blockDim.x + threadIdx.x;
    if (e >= E) return;
    int s = src[e], d = dst[e];
    int pos = row_ptr[d] + atomicAdd(&cursor[d], 1);
    col[pos] = s;
    wgt[pos] = dinv[s] * dinv[d];
}

__global__ __launch_bounds__(256) void k_gather(
    const float4* __restrict__ X4, const float* __restrict__ dinv,
    const int* __restrict__ row_ptr, const int* __restrict__ cnt,
    const int* __restrict__ col, const float* __restrict__ wgt,
    float4* __restrict__ agg4, int N)
{
    int t = blockIdx.x * blockDim.x + threadIdx.x;
    int node = t >> 5;
    if (node >= N) return;
    int lane = t & 31;
    float ds = dinv[node];
    float w0 = ds * ds;
    float4 acc = X4[(size_t)node * 32 + lane];
    acc.x *= w0; acc.y *= w0; acc.z *= w0; acc.w *= w0;
    int beg = row_ptr[node];
    int m = cnt[node];
    for (int j = 0; j < m; ++j) {
        int s0 = col[beg + j];
        float wa = wgt[beg + j];
        float4 v0 = X4[(size_t)s0 * 32 + lane];
        acc.x = fmaf(wa, v0.x, acc.x); acc.y = fmaf(wa, v0.y, acc.y);
        acc.z = fmaf(wa, v0.z, acc.z); acc.w = fmaf(wa, v0.w, acc.w);
    }
    agg4[(size_t)node * 32 + lane] = acc;
}

__global__ __launch_bounds__(256) void k_gemm_couple(
    const float* A, const float* __restrict__ Ws, const float* __restrict__ bs,
    const float* __restrict__ Wt, const float* __restrict__ bt,
    const float* __restrict__ Xo, float* Out, int N)
{
    constexpr int TM = 64, TK = 16;
    __shared__ float As[TK][TM + 4];
    __shared__ float Ss[TK][DIMS];
    __shared__ float St[TK][DIMS];
    const int tid = threadIdx.x;
    const int ty = tid >> 4, tx = tid & 15;
    const int r0 = ty * 4, c0 = tx * 8;
    const int block_row = blockIdx.x * TM;

    float acc_s[4][8], acc_t[4][8];
#pragma unroll
    for (int r = 0; r < 4; ++r)
#pragma unroll
        for (int c = 0; c < 8; ++c) { acc_s[r][c] = 0.f; acc_t[r][c] = 0.f; }

    const int ar = tid >> 2;
    const int aq = tid & 3;
    int arow = block_row + ar;
    if (arow >= N) arow = N - 1;

    for (int k0 = 0; k0 < DIMS; k0 += TK) {
        __syncthreads();
        {
            float4 v = *(const float4*)&A[(size_t)arow * DIMS + k0 + aq * 4];
            As[aq * 4 + 0][ar] = v.x;
            As[aq * 4 + 1][ar] = v.y;
            As[aq * 4 + 2][ar] = v.z;
            As[aq * 4 + 3][ar] = v.w;
        }
#pragma unroll
        for (int i = 0; i < 2; ++i) {
            int idx = tid + i * 256;
            int kk = idx >> 5;
            int j4 = idx & 31;
            *(float4*)&Ss[kk][j4 * 4] = *(const float4*)&Ws[(size_t)(k0 + kk) * DIMS + j4 * 4];
            *(float4*)&St[kk][j4 * 4] = *(const float4*)&Wt[(size_t)(k0 + kk) * DIMS + j4 * 4];
        }
        __syncthreads();
#pragma unroll
        for (int k = 0; k < TK; ++k) {
            float4 av = *(const float4*)&As[k][r0];
            float a[4] = {av.x, av.y, av.z, av.w};
            float ws8[8], wt8[8];
            *(float4*)&ws8[0] = *(const float4*)&Ss[k][c0];
            *(float4*)&ws8[4] = *(const float4*)&Ss[k][c0 + 4];
            *(float4*)&wt8[0] = *(const float4*)&St[k][c0];
            *(float4*)&wt8[4] = *(const float4*)&St[k][c0 + 4];
#pragma unroll
            for (int r = 0; r < 4; ++r)
#pragma unroll
                for (int c = 0; c < 8; ++c) {
                    acc_s[r][c] = fmaf(a[r], ws8[c], acc_s[r][c]);
                    acc_t[r][c] = fmaf(a[r], wt8[c], acc_t[r][c]);
                }
        }
    }

    float bsv[8], btv[8];
    *(float4*)&bsv[0] = *(const float4*)&bs[c0];
    *(float4*)&bsv[4] = *(const float4*)&bs[c0 + 4];
    *(float4*)&btv[0] = *(const float4*)&bt[c0];
    *(float4*)&btv[4] = *(const float4*)&bt[c0 + 4];
#pragma unroll
    for (int r = 0; r < 4; ++r) {
        int row = block_row + r0 + r;
        if (row < N) {
            float xo[8];
            *(float4*)&xo[0] = *(const float4*)&Xo[(size_t)row * DIMS + c0];
            *(float4*)&xo[4] = *(const float4*)&Xo[(size_t)row * DIMS + c0 + 4];
            float o[8];
#pragma unroll
            for (int c = 0; c < 8; ++c) {
                float s = tanhf(acc_s[r][c] + bsv[c]);
                float t = acc_t[r][c] + btv[c];
                o[c] = xo[c] * expf(s) + t;
            }
            *(float4*)&Out[(size_t)row * DIMS + c0] = *(const float4*)&o[0];
            *(float4*)&Out[(size_t)row * DIMS + c0 + 4] = *(const float4*)&o[4];
        }
    }
}

extern "C" void kernel_launch(void* const* d_in, const int* in_sizes, int n_in,
                              void* d_out, int out_size, void* d_ws, size_t ws_size,
                              hipStream_t stream) {
    const float* x_main  = (const float*)d_in[0];
    const float* x_guide = (const float*)d_in[1];
    const int*   ei      = (const int*)d_in[2];
    const float* Ws1 = (const float*)d_in[3];
    const float* bs1 = (const float*)d_in[4];
    const float* Wt1 = (const float*)d_in[5];
    const float* bt1 = (const float*)d_in[6];
    const float* Ws2 = (const float*)d_in[7];
    const float* bs2 = (const float*)d_in[8];
    const float* Wt2 = (const float*)d_in[9];
    const float* bt2 = (const float*)d_in[10];

    const int N = in_sizes[0] / DIMS;
    const int E = in_sizes[2] / 2;
    const int* src = ei;
    const int* dst = ei + E;

    float* out_main  = (float*)d_out;
    float* out_guide = out_main + (size_t)N * DIMS;

    // ---- ws layout ----
    char* w = (char*)d_ws;
    size_t off = 0;
    auto alloc = [&](size_t bytes) { size_t o = off; off = (off + bytes + 15) & ~(size_t)15; return o; };
    int*   cnt     = (int*)(w + alloc((size_t)N * 4));
    int*   row_ptr = (int*)(w + alloc((size_t)N * 4));
    int*   bump    = (int*)(w + alloc(64));
    float* dinv    = (float*)(w + alloc((size_t)N * 4));
    int*   col     = (int*)(w + alloc((size_t)E * 4));
    size_t base_end = off;
    // MFMA path extras
    unsigned short* xb   = (unsigned short*)(w + alloc((size_t)N * DIMS * 2));
    unsigned short* aggb = (unsigned short*)(w + alloc((size_t)N * DIMS * 2));
    unsigned short* wpk  = (unsigned short*)(w + alloc((size_t)4 * 16384 * 2));
    size_t needed_mfma = off;
    int* slot = (int*)aggb;   // slot[E] aliases aggb (consumed by k_fill3 before gather writes aggb)
    // f32 fallback extras (overlap the MFMA region)
    int*   cursor_fb = (int*)(w + base_end);
    float* wgt_fb    = (float*)(w + base_end + ((size_t)N * 4 + 15 & ~(size_t)15));
    size_t needed_f32 = base_end + ((size_t)N * 4 + 16) + (size_t)E * 4;

    const int gemm_grid  = (N + 63) / 64;
    const int ntiles64   = (N + 63) / 64;
    const int mfma_grid  = (ntiles64 < 512) ? ntiles64 : 512;

    if (ws_size >= needed_mfma) {
        // ---- CSR build (atomic-free fill via slot-from-count) ----
        hipMemsetAsync(cnt, 0, ((char*)(bump + 16)) - (char*)cnt, stream);
        k_count_slot<<<(E + 255) / 256, 256, 0, stream>>>(dst, cnt, slot, E);
        k_dinv2<<<(N + 255) / 256, 256, 0, stream>>>(cnt, dinv, N);
        k_alloc<<<(N + 255) / 256, 256, 0, stream>>>(cnt, row_ptr, bump, N);
        k_fill3<<<(E + 255) / 256, 256, 0, stream>>>(src, dst, row_ptr, slot, col, E);

        unsigned short* W1pk = wpk;              // [Ws1 | Wt1]
        unsigned short* W2pk = wpk + 2 * 16384;  // [Ws2 | Wt2]
        k_wpack1<<<8, 256, 0, stream>>>(Ws1, W1pk);
        k_wpack1<<<8, 256, 0, stream>>>(Wt1, W1pk + 16384);
        k_wpack1<<<8, 256, 0, stream>>>(Ws2, W2pk);
        k_wpack1<<<8, 256, 0, stream>>>(Wt2, W2pk + 16384);

        const int n8 = N * DIMS / 8;
        k_cast<<<(n8 + 255) / 256, 256, 0, stream>>>(x_guide, xb, n8);

        const int gather_grid = (N * 16 + 255) / 256;
        // ---- stage 1 ----
        k_gather_b3<<<gather_grid, 256, 0, stream>>>(xb, dinv, row_ptr, cnt, col, aggb, N);
        k_mfma_couple3<<<mfma_grid, 256, 0, stream>>>(aggb, W1pk, bs1, bt1, x_main,
                                                      out_main, xb, N, ntiles64);
        // ---- stage 2 ----
        k_gather_b3<<<gather_grid, 256, 0, stream>>>(xb, dinv, row_ptr, cnt, col, aggb, N);
        k_mfma_couple3<<<mfma_grid, 256, 0, stream>>>(aggb, W2pk, bs2, bt2, x_guide,
                                                      out_guide, nullptr, N, ntiles64);
    } else if (ws_size >= needed_f32) {
        // ---- fallback: round-2 f32 path (agg aliases out_guide) ----
        float* agg = out_guide;
        hipMemsetAsync(cnt, 0, ((char*)(bump + 16)) - (char*)cnt, stream);
        hipMemsetAsync(cursor_fb, 0, (size_t)N * 4, stream);
        k_count_slot<<<(E + 255) / 256, 256, 0, stream>>>(dst, cnt, (int*)col, E); // col as dummy slot
        k_dinv2<<<(N + 255) / 256, 256, 0, stream>>>(cnt, dinv, N);
        k_alloc<<<(N + 255) / 256, 256, 0, stream>>>(cnt, row_ptr, bump, N);
        k_fill<<<(E + 255) / 256, 256, 0, stream>>>(src, dst, row_ptr, cursor_fb, dinv, col, wgt_fb, E);
        const int gather_grid32 = (N * 32 + 255) / 256;
        k_gather<<<gather_grid32, 256, 0, stream>>>((const float4*)x_guide, dinv, row_ptr, cnt,
                                                    col, wgt_fb, (float4*)agg, N);
        k_gemm_couple<<<gemm_grid, 256, 0, stream>>>(agg, Ws1, bs1, Wt1, bt1, x_main, out_main, N);
        k_gather<<<gather_grid32, 256, 0, stream>>>((const float4*)out_main, dinv, row_ptr, cnt,
                                                    col, wgt_fb, (float4*)agg, N);
        k_gemm_couple<<<gemm_grid, 256, 0, stream>>>(agg, Ws2, bs2, Wt2, bt2, x_guide, out_guide, N);
    }
}